// Round 7
// baseline (73.576 us; speedup 1.0000x reference)
//
#include <hip/hip_runtime.h>
#include <hip/hip_fp16.h>
#include <math.h>

// Problem constants (from reference)
#define B_SZ 8192
#define L_SZ 50
#define D_SZ 128
#define C_SZ 256        // output cols of W_cpr
#define K_SZ 256        // = 2*D, GEMM K
#define R_SZ 7
#define V_SZ 100000
#define BR   32         // batch rows per block
#define NT   512        // 8 waves

// ---------------------------------------------------------------------------
// Kernel A: convert emb f32 [V][128] -> fp16 table in ws. 77 MB streaming.
// ---------------------------------------------------------------------------
__global__ __launch_bounds__(256) void k_convert(const float* __restrict__ src,
                                                 __half* __restrict__ dst,
                                                 int n4) {
    int i = blockIdx.x * 256 + threadIdx.x;
    if (i >= n4) return;
    float4 v = ((const float4*)src)[i];
    union { __half2 h[2]; uint2 u; } pk;
    pk.h[0].x = __float2half_rn(v.x); pk.h[0].y = __float2half_rn(v.y);
    pk.h[1].x = __float2half_rn(v.z); pk.h[1].y = __float2half_rn(v.w);
    ((uint2*)dst)[i] = pk.u;
}

// ---------------------------------------------------------------------------
// Kernel B: transpose W_cpr [C][K] -> Wt [K][C], LDS-tiled. 256 KB, ~2 us.
// ---------------------------------------------------------------------------
__global__ __launch_bounds__(256) void k_transpose(const float* __restrict__ W,
                                                   float* __restrict__ Wt) {
    __shared__ float t[32][33];
    const int tx = threadIdx.x & 31;
    const int ty = threadIdx.x >> 5;  // 0..7
    const int k0 = blockIdx.x * 32;
    const int c0 = blockIdx.y * 32;
#pragma unroll
    for (int i = 0; i < 32; i += 8)
        t[ty + i][tx] = W[(size_t)(c0 + ty + i) * K_SZ + k0 + tx];
    __syncthreads();
#pragma unroll
    for (int i = 0; i < 32; i += 8)
        Wt[(size_t)(k0 + ty + i) * C_SZ + c0 + tx] = t[tx][ty + i];
}

// ---------------------------------------------------------------------------
// Fused kernel (fp16 table): gather + GEMM + LeakyReLU + head + log-softmax.
//
// Gather: 8 streams/wave (4 rows x 2 sides). POP4 pops up to 4 tokens of a
// stream with ONE load instruction: 16-lane group g reads token jg's 256 B
// row (16 x float4 of packed halves); pad groups re-read j0 with scale 0.
// f32 accumulate; cross-group reduce via shfl_xor(16/32) at the end.
// GEMM: identical to the proven R6 shape (64 col-grp x 8 row-grp, acc[4][4]).
// ---------------------------------------------------------------------------
__global__ __launch_bounds__(512, 2) void k_fused_h(
    const int* __restrict__ ltok, const int* __restrict__ rtok,
    const int* __restrict__ lmask, const int* __restrict__ rmask,
    const __half* __restrict__ E16, const float* __restrict__ Wt,
    const float* __restrict__ b_cpr, const float* __restrict__ W_sm,
    const float* __restrict__ b_sm, float* __restrict__ out) {

    __shared__ float X_lds[BR][K_SZ];        // 32 KB
    __shared__ float h_lds[BR][C_SZ + 4];    // 33.3 KB
    __shared__ float part[BR][R_SZ][2];
    __shared__ float l_lds[BR][R_SZ];

    const int tid = threadIdx.x;
    const int wave = tid >> 6;
    const int lane = tid & 63;
    const int grp = lane >> 4;   // 16-lane group 0..3
    const int sub = lane & 15;   // float4 slot within a 256 B row
    const int row0 = blockIdx.x * BR;

    // ---------------- gather phase: 4 rows per wave ----------------
    const int rbase = row0 + wave * 4;
    int lt0 = 0, lt1 = 0, lt2 = 0, lt3 = 0;
    int rt0 = 0, rt1 = 0, rt2 = 0, rt3 = 0;
    int lm0 = 0, lm1 = 0, lm2 = 0, lm3 = 0;
    int rm0 = 0, rm1 = 0, rm2 = 0, rm3 = 0;
    if (lane < L_SZ) {
        const size_t o = (size_t)rbase * L_SZ + lane;
        lt0 = ltok[o];            lm0 = lmask[o];
        lt1 = ltok[o + L_SZ];     lm1 = lmask[o + L_SZ];
        lt2 = ltok[o + 2 * L_SZ]; lm2 = lmask[o + 2 * L_SZ];
        lt3 = ltok[o + 3 * L_SZ]; lm3 = lmask[o + 3 * L_SZ];
        rt0 = rtok[o];            rm0 = rmask[o];
        rt1 = rtok[o + L_SZ];     rm1 = rmask[o + L_SZ];
        rt2 = rtok[o + 2 * L_SZ]; rm2 = rmask[o + 2 * L_SZ];
        rt3 = rtok[o + 3 * L_SZ]; rm3 = rmask[o + 3 * L_SZ];
    }
    unsigned long long bL0 = __ballot(lm0 != 0), bL1 = __ballot(lm1 != 0);
    unsigned long long bL2 = __ballot(lm2 != 0), bL3 = __ballot(lm3 != 0);
    unsigned long long bR0 = __ballot(rm0 != 0), bR1 = __ballot(rm1 != 0);
    unsigned long long bR2 = __ballot(rm2 != 0), bR3 = __ballot(rm3 != 0);

    const float4* E = (const float4*)E16;  // [V][16] float4 (8 halves each)
    float aL0[8] = {0}, aL1[8] = {0}, aL2[8] = {0}, aL3[8] = {0};
    float aR0[8] = {0}, aR1[8] = {0}, aR2[8] = {0}, aR3[8] = {0};

    // Pop up to 4 tokens of one stream with a single wave load.
#define POP4(bal, tok, A)                                               \
    if (bal) {                                                          \
        unsigned long long b_ = bal;                                    \
        const int j0 = __ffsll(b_) - 1; b_ &= b_ - 1;                   \
        int j1 = j0, j2 = j0, j3 = j0, n_ = 1;                          \
        if (b_) { j1 = __ffsll(b_) - 1; b_ &= b_ - 1; n_ = 2;           \
            if (b_) { j2 = __ffsll(b_) - 1; b_ &= b_ - 1; n_ = 3;       \
                if (b_) { j3 = __ffsll(b_) - 1; b_ &= b_ - 1; n_ = 4; } \
                else j3 = j2;                                           \
            } else { j2 = j1; j3 = j1; }                                \
        }                                                               \
        bal = b_;                                                       \
        const int jg = (grp == 0) ? j0 : (grp == 1) ? j1                \
                     : (grp == 2) ? j2 : j3;                            \
        const int t_ = __shfl(tok, jg);                                 \
        const float4 ev = E[((size_t)t_ << 4) + sub];                   \
        const float sc = (grp < n_) ? 1.f : 0.f;                        \
        const __half2* hp = (const __half2*)&ev;                        \
        _Pragma("unroll")                                               \
        for (int q = 0; q < 4; ++q) {                                   \
            const float fx = __half2float(hp[q].x);                     \
            const float fy = __half2float(hp[q].y);                     \
            A[2 * q]     = fmaf(sc, fx, A[2 * q]);                      \
            A[2 * q + 1] = fmaf(sc, fy, A[2 * q + 1]);                  \
        }                                                               \
    }

    while (bL0 | bL1 | bL2 | bL3 | bR0 | bR1 | bR2 | bR3) {
        POP4(bL0, lt0, aL0)
        POP4(bL1, lt1, aL1)
        POP4(bL2, lt2, aL2)
        POP4(bL3, lt3, aL3)
        POP4(bR0, rt0, aR0)
        POP4(bR1, rt1, aR1)
        POP4(bR2, rt2, aR2)
        POP4(bR3, rt3, aR3)
    }
#undef POP4

    // reduce across the 4 groups (lanes sharing `sub`)
#define RED(A)                                       \
    _Pragma("unroll")                                \
    for (int j = 0; j < 8; ++j) {                    \
        A[j] += __shfl_xor(A[j], 16);                \
        A[j] += __shfl_xor(A[j], 32);                \
    }
    RED(aL0) RED(aL1) RED(aL2) RED(aL3)
    RED(aR0) RED(aR1) RED(aR2) RED(aR3)
#undef RED

    // write X: row dims [0,128)=left, [128,256)=right; group g owns row g
    {
        const int r = wave * 4;
#define ST(A, row, side)                                                   \
        *(float4*)&X_lds[row][(side) * 128 + sub * 8] =                    \
            make_float4(A[0], A[1], A[2], A[3]);                           \
        *(float4*)&X_lds[row][(side) * 128 + sub * 8 + 4] =                \
            make_float4(A[4], A[5], A[6], A[7]);
        if (grp == 0)      { ST(aL0, r + 0, 0) ST(aR0, r + 0, 1) }
        else if (grp == 1) { ST(aL1, r + 1, 0) ST(aR1, r + 1, 1) }
        else if (grp == 2) { ST(aL2, r + 2, 0) ST(aR2, r + 2, 1) }
        else               { ST(aL3, r + 3, 0) ST(aR3, r + 3, 1) }
#undef ST
    }
    __syncthreads();

    // ---------------- GEMM phase: 64 col-groups x 8 row-groups, R=4 --------
    const int cc = (tid & 63) * 4;        // 4 output cols
    const int rr = (tid >> 6) * 4;        // 4 rows
    float acc[4][4] = {{0.f}};
#pragma unroll 2
    for (int k = 0; k < K_SZ; k += 4) {
        float4 w0 = *(const float4*)&Wt[(k + 0) * C_SZ + cc];
        float4 w1 = *(const float4*)&Wt[(k + 1) * C_SZ + cc];
        float4 w2 = *(const float4*)&Wt[(k + 2) * C_SZ + cc];
        float4 w3 = *(const float4*)&Wt[(k + 3) * C_SZ + cc];
        float ws[4][4] = {{w0.x, w0.y, w0.z, w0.w}, {w1.x, w1.y, w1.z, w1.w},
                          {w2.x, w2.y, w2.z, w2.w}, {w3.x, w3.y, w3.z, w3.w}};
#pragma unroll
        for (int i = 0; i < 4; ++i) {
            float4 xv = *(const float4*)&X_lds[rr + i][k];  // broadcast
            float xs[4] = {xv.x, xv.y, xv.z, xv.w};
#pragma unroll
            for (int kk = 0; kk < 4; ++kk) {
#pragma unroll
                for (int j = 0; j < 4; ++j)
                    acc[i][j] = fmaf(xs[kk], ws[kk][j], acc[i][j]);
            }
        }
    }

    // bias + LeakyReLU -> LDS
#pragma unroll
    for (int i = 0; i < 4; ++i) {
        float4 hv;
        float* hp = (float*)&hv;
#pragma unroll
        for (int j = 0; j < 4; ++j) {
            float h = acc[i][j] + b_cpr[cc + j];
            hp[j] = (h >= 0.f) ? h : 0.01f * h;
        }
        *(float4*)&h_lds[rr + i][cc] = hv;
    }
    __syncthreads();

    // ---------------- head: K-split partial dots (2 chunks of 128) --------
    if (tid < BR * R_SZ * 2) {            // 448 threads: (bl, r, chunk)
        const int chunk = tid & 1;
        const int rh = (tid >> 1) % R_SZ;
        const int bl = tid / (R_SZ * 2);
        const float* wr = W_sm + rh * C_SZ;
        const int c0 = chunk * 128;
        float s = 0.f;
#pragma unroll
        for (int c = 0; c < 128; c += 4) {
            float4 hv = *(const float4*)&h_lds[bl][c0 + c];
            s = fmaf(hv.x, wr[c0 + c + 0], s);
            s = fmaf(hv.y, wr[c0 + c + 1], s);
            s = fmaf(hv.z, wr[c0 + c + 2], s);
            s = fmaf(hv.w, wr[c0 + c + 3], s);
        }
        part[bl][rh][chunk] = s;
    }
    __syncthreads();

    if (tid < BR * R_SZ) {                // 224 threads: combine + bias
        const int bl = tid / R_SZ;
        const int rh = tid % R_SZ;
        l_lds[bl][rh] = part[bl][rh][0] + part[bl][rh][1] + b_sm[rh];
    }
    __syncthreads();

    // ---------------- log-softmax over R=7 ----------------
    if (tid < BR) {
        float m = -INFINITY;
#pragma unroll
        for (int rh = 0; rh < R_SZ; ++rh) m = fmaxf(m, l_lds[tid][rh]);
        float se = 0.f;
#pragma unroll
        for (int rh = 0; rh < R_SZ; ++rh) se += expf(l_lds[tid][rh] - m);
        const float lse = m + logf(se);
        const size_t ob = (size_t)(row0 + tid) * R_SZ;
#pragma unroll
        for (int rh = 0; rh < R_SZ; ++rh) out[ob + rh] = l_lds[tid][rh] - lse;
    }
}

// ---------------------------------------------------------------------------
// Fallback fused kernel (f32 table) — the proven R6 kernel, used only if ws
// is too small for the fp16 table.
// ---------------------------------------------------------------------------
__global__ __launch_bounds__(512, 2) void k_fused_f32(
    const int* __restrict__ ltok, const int* __restrict__ rtok,
    const int* __restrict__ lmask, const int* __restrict__ rmask,
    const float* __restrict__ emb, const float* __restrict__ Wt,
    const float* __restrict__ b_cpr, const float* __restrict__ W_sm,
    const float* __restrict__ b_sm, float* __restrict__ out) {

    __shared__ float X_lds[BR][K_SZ];
    __shared__ float h_lds[BR][C_SZ + 4];
    __shared__ float part[BR][R_SZ][2];
    __shared__ float l_lds[BR][R_SZ];

    const int tid = threadIdx.x;
    const int wave = tid >> 6;
    const int lane = tid & 63;
    const int hlane = lane & 31;
    const int row0 = blockIdx.x * BR;

    const int rbase = row0 + wave * 4;
    int lt0 = 0, lt1 = 0, lt2 = 0, lt3 = 0;
    int rt0 = 0, rt1 = 0, rt2 = 0, rt3 = 0;
    int lm0 = 0, lm1 = 0, lm2 = 0, lm3 = 0;
    int rm0 = 0, rm1 = 0, rm2 = 0, rm3 = 0;
    if (lane < L_SZ) {
        const size_t o = (size_t)rbase * L_SZ + lane;
        lt0 = ltok[o];            lm0 = lmask[o];
        lt1 = ltok[o + L_SZ];     lm1 = lmask[o + L_SZ];
        lt2 = ltok[o + 2 * L_SZ]; lm2 = lmask[o + 2 * L_SZ];
        lt3 = ltok[o + 3 * L_SZ]; lm3 = lmask[o + 3 * L_SZ];
        rt0 = rtok[o];            rm0 = rmask[o];
        rt1 = rtok[o + L_SZ];     rm1 = rmask[o + L_SZ];
        rt2 = rtok[o + 2 * L_SZ]; rm2 = rmask[o + 2 * L_SZ];
        rt3 = rtok[o + 3 * L_SZ]; rm3 = rmask[o + 3 * L_SZ];
    }
    unsigned long long bL0 = __ballot(lm0 != 0), bL1 = __ballot(lm1 != 0);
    unsigned long long bL2 = __ballot(lm2 != 0), bL3 = __ballot(lm3 != 0);
    unsigned long long bR0 = __ballot(rm0 != 0), bR1 = __ballot(rm1 != 0);
    unsigned long long bR2 = __ballot(rm2 != 0), bR3 = __ballot(rm3 != 0);

    const float4* emb4 = (const float4*)emb;
    float4 aL0 = {0, 0, 0, 0}, aL1 = {0, 0, 0, 0};
    float4 aL2 = {0, 0, 0, 0}, aL3 = {0, 0, 0, 0};
    float4 aR0 = {0, 0, 0, 0}, aR1 = {0, 0, 0, 0};
    float4 aR2 = {0, 0, 0, 0}, aR3 = {0, 0, 0, 0};

#define POP2(bal, tok, e, sc, hv)                                   \
    {                                                               \
        hv = (bal != 0);                                            \
        if (hv) {                                                   \
            int i1 = __ffsll(bal) - 1; bal &= bal - 1;              \
            bool has2 = (bal != 0);                                 \
            int i2 = has2 ? (__ffsll(bal) - 1) : i1;                \
            if (has2) bal &= bal - 1;                               \
            int ts = __shfl(tok, (lane < 32) ? i1 : i2);            \
            e = emb4[((unsigned)ts << 5) + hlane];                  \
            sc = (lane < 32 || has2) ? 1.f : 0.f;                   \
        }                                                           \
    }
#define ACC4(a, s, e)                                               \
    { a.x = fmaf(s, e.x, a.x); a.y = fmaf(s, e.y, a.y);             \
      a.z = fmaf(s, e.z, a.z); a.w = fmaf(s, e.w, a.w); }

    while (bL0 | bL1 | bL2 | bL3 | bR0 | bR1 | bR2 | bR3) {
        float4 e0, e1, e2, e3, e4, e5, e6, e7;
        float s0, s1, s2, s3, s4, s5, s6, s7;
        bool h0, h1, h2, h3, h4, h5, h6, h7;
        POP2(bL0, lt0, e0, s0, h0)
        POP2(bL1, lt1, e1, s1, h1)
        POP2(bL2, lt2, e2, s2, h2)
        POP2(bL3, lt3, e3, s3, h3)
        POP2(bR0, rt0, e4, s4, h4)
        POP2(bR1, rt1, e5, s5, h5)
        POP2(bR2, rt2, e6, s6, h6)
        POP2(bR3, rt3, e7, s7, h7)
        if (h0) ACC4(aL0, s0, e0)
        if (h1) ACC4(aL1, s1, e1)
        if (h2) ACC4(aL2, s2, e2)
        if (h3) ACC4(aL3, s3, e3)
        if (h4) ACC4(aR0, s4, e4)
        if (h5) ACC4(aR1, s5, e5)
        if (h6) ACC4(aR2, s6, e6)
        if (h7) ACC4(aR3, s7, e7)
    }
#undef POP2
#undef ACC4

#define XHALF(a)                          \
    a.x += __shfl_xor(a.x, 32);           \
    a.y += __shfl_xor(a.y, 32);           \
    a.z += __shfl_xor(a.z, 32);           \
    a.w += __shfl_xor(a.w, 32);
    XHALF(aL0) XHALF(aL1) XHALF(aL2) XHALF(aL3)
    XHALF(aR0) XHALF(aR1) XHALF(aR2) XHALF(aR3)
#undef XHALF

    {
        const int slot = (lane < 32) ? hlane : (32 + hlane);
        ((float4*)&X_lds[rbase - row0 + 0][0])[slot] = (lane < 32) ? aL0 : aR0;
        ((float4*)&X_lds[rbase - row0 + 1][0])[slot] = (lane < 32) ? aL1 : aR1;
        ((float4*)&X_lds[rbase - row0 + 2][0])[slot] = (lane < 32) ? aL2 : aR2;
        ((float4*)&X_lds[rbase - row0 + 3][0])[slot] = (lane < 32) ? aL3 : aR3;
    }
    __syncthreads();

    const int cc = (tid & 63) * 4;
    const int rr = (tid >> 6) * 4;
    float acc[4][4] = {{0.f}};
#pragma unroll 2
    for (int k = 0; k < K_SZ; k += 4) {
        float4 w0 = *(const float4*)&Wt[(k + 0) * C_SZ + cc];
        float4 w1 = *(const float4*)&Wt[(k + 1) * C_SZ + cc];
        float4 w2 = *(const float4*)&Wt[(k + 2) * C_SZ + cc];
        float4 w3 = *(const float4*)&Wt[(k + 3) * C_SZ + cc];
        float ws[4][4] = {{w0.x, w0.y, w0.z, w0.w}, {w1.x, w1.y, w1.z, w1.w},
                          {w2.x, w2.y, w2.z, w2.w}, {w3.x, w3.y, w3.z, w3.w}};
#pragma unroll
        for (int i = 0; i < 4; ++i) {
            float4 xv = *(const float4*)&X_lds[rr + i][k];
            float xs[4] = {xv.x, xv.y, xv.z, xv.w};
#pragma unroll
            for (int kk = 0; kk < 4; ++kk) {
#pragma unroll
                for (int j = 0; j < 4; ++j)
                    acc[i][j] = fmaf(xs[kk], ws[kk][j], acc[i][j]);
            }
        }
    }

#pragma unroll
    for (int i = 0; i < 4; ++i) {
        float4 hv;
        float* hp = (float*)&hv;
#pragma unroll
        for (int j = 0; j < 4; ++j) {
            float h = acc[i][j] + b_cpr[cc + j];
            hp[j] = (h >= 0.f) ? h : 0.01f * h;
        }
        *(float4*)&h_lds[rr + i][cc] = hv;
    }
    __syncthreads();

    if (tid < BR * R_SZ * 2) {
        const int chunk = tid & 1;
        const int rh = (tid >> 1) % R_SZ;
        const int bl = tid / (R_SZ * 2);
        const float* wr = W_sm + rh * C_SZ;
        const int c0 = chunk * 128;
        float s = 0.f;
#pragma unroll
        for (int c = 0; c < 128; c += 4) {
            float4 hv = *(const float4*)&h_lds[bl][c0 + c];
            s = fmaf(hv.x, wr[c0 + c + 0], s);
            s = fmaf(hv.y, wr[c0 + c + 1], s);
            s = fmaf(hv.z, wr[c0 + c + 2], s);
            s = fmaf(hv.w, wr[c0 + c + 3], s);
        }
        part[bl][rh][chunk] = s;
    }
    __syncthreads();

    if (tid < BR * R_SZ) {
        const int bl = tid / R_SZ;
        const int rh = tid % R_SZ;
        l_lds[bl][rh] = part[bl][rh][0] + part[bl][rh][1] + b_sm[rh];
    }
    __syncthreads();

    if (tid < BR) {
        float m = -INFINITY;
#pragma unroll
        for (int rh = 0; rh < R_SZ; ++rh) m = fmaxf(m, l_lds[tid][rh]);
        float se = 0.f;
#pragma unroll
        for (int rh = 0; rh < R_SZ; ++rh) se += expf(l_lds[tid][rh] - m);
        const float lse = m + logf(se);
        const size_t ob = (size_t)(row0 + tid) * R_SZ;
#pragma unroll
        for (int rh = 0; rh < R_SZ; ++rh) out[ob + rh] = l_lds[tid][rh] - lse;
    }
}

// ---------------------------------------------------------------------------
extern "C" void kernel_launch(void* const* d_in, const int* in_sizes, int n_in,
                              void* d_out, int out_size, void* d_ws, size_t ws_size,
                              hipStream_t stream) {
    const int* ltok = (const int*)d_in[0];
    const int* rtok = (const int*)d_in[1];
    const int* lmask = (const int*)d_in[2];
    const int* rmask = (const int*)d_in[3];
    const float* emb = (const float*)d_in[4];
    const float* W_cpr = (const float*)d_in[5];
    const float* b_cpr = (const float*)d_in[6];
    const float* W_sm = (const float*)d_in[7];
    const float* b_sm = (const float*)d_in[8];
    float* out = (float*)d_out;

    const size_t E16_BYTES = (size_t)V_SZ * D_SZ * sizeof(__half);  // 25.6 MB
    const size_t WT_BYTES = (size_t)K_SZ * C_SZ * sizeof(float);    // 256 KB

    if (ws_size >= E16_BYTES + WT_BYTES) {
        __half* E16 = (__half*)d_ws;
        float* Wt = (float*)((char*)d_ws + E16_BYTES);
        const int n4 = V_SZ * D_SZ / 4;
        k_convert<<<(n4 + 255) / 256, 256, 0, stream>>>(emb, E16, n4);
        k_transpose<<<dim3(K_SZ / 32, C_SZ / 32), 256, 0, stream>>>(W_cpr, Wt);
        k_fused_h<<<B_SZ / BR, NT, 0, stream>>>(ltok, rtok, lmask, rmask, E16,
                                                Wt, b_cpr, W_sm, b_sm, out);
    } else {
        float* Wt = (float*)d_ws;
        k_transpose<<<dim3(K_SZ / 32, C_SZ / 32), 256, 0, stream>>>(W_cpr, Wt);
        k_fused_f32<<<B_SZ / BR, NT, 0, stream>>>(ltok, rtok, lmask, rmask, emb,
                                                  Wt, b_cpr, W_sm, b_sm, out);
    }
}

// Round 8
// 60.662 us; speedup vs baseline: 1.2129x; 1.2129x over previous
//
#include <hip/hip_runtime.h>
#include <hip/hip_fp16.h>
#include <math.h>

// Problem constants (from reference)
#define B_SZ 8192
#define L_SZ 50
#define D_SZ 128
#define C_SZ 256        // output cols of W_cpr
#define K_SZ 256        // = 2*D, GEMM K
#define R_SZ 7
#define V_SZ 100000
#define BR   32         // batch rows per block
#define NT   512        // 8 waves
#define NW   8          // waves per block

// ---------------------------------------------------------------------------
// Kernel A: convert emb f32 [V][128] -> fp16 table in ws. 77 MB streaming.
// ---------------------------------------------------------------------------
__global__ __launch_bounds__(256) void k_convert(const float* __restrict__ src,
                                                 __half* __restrict__ dst,
                                                 int n4) {
    int i = blockIdx.x * 256 + threadIdx.x;
    if (i >= n4) return;
    float4 v = ((const float4*)src)[i];
    union { __half2 h[2]; uint2 u; } pk;
    pk.h[0].x = __float2half_rn(v.x); pk.h[0].y = __float2half_rn(v.y);
    pk.h[1].x = __float2half_rn(v.z); pk.h[1].y = __float2half_rn(v.w);
    ((uint2*)dst)[i] = pk.u;
}

// ---------------------------------------------------------------------------
// Kernel B: transpose W_cpr [C][K] -> Wt [K][C], LDS-tiled. 256 KB, ~2 us.
// ---------------------------------------------------------------------------
__global__ __launch_bounds__(256) void k_transpose(const float* __restrict__ W,
                                                   float* __restrict__ Wt) {
    __shared__ float t[32][33];
    const int tx = threadIdx.x & 31;
    const int ty = threadIdx.x >> 5;  // 0..7
    const int k0 = blockIdx.x * 32;
    const int c0 = blockIdx.y * 32;
#pragma unroll
    for (int i = 0; i < 32; i += 8)
        t[ty + i][tx] = W[(size_t)(c0 + ty + i) * K_SZ + k0 + tx];
    __syncthreads();
#pragma unroll
    for (int i = 0; i < 32; i += 8)
        Wt[(size_t)(k0 + ty + i) * C_SZ + c0 + tx] = t[tx][ty + i];
}

// ---------------------------------------------------------------------------
// Fused kernel (fp16 table): gather + GEMM + LeakyReLU + head + log-softmax.
//
// Gather restructured vs R7: token lists are COMPACTED into LDS up front
// (ballot + prefix popcount), so the hot loop is a single basic block with
// 8 independent, UNCONDITIONAL 256 B row loads per iteration -> all 8 in
// flight per wave (R7's per-stream `if` blocks serialized them).
// 16-lane group g handles token (it*4+g) of each stream; exhausted streams
// re-read a clamped index with scale 0 (cheap L1 hit).
// ---------------------------------------------------------------------------
__global__ __launch_bounds__(512, 2) void k_fused_h(
    const int* __restrict__ ltok, const int* __restrict__ rtok,
    const int* __restrict__ lmask, const int* __restrict__ rmask,
    const __half* __restrict__ E16, const float* __restrict__ Wt,
    const float* __restrict__ b_cpr, const float* __restrict__ W_sm,
    const float* __restrict__ b_sm, float* __restrict__ out) {

    __shared__ float X_lds[BR][K_SZ];        // 32 KB
    __shared__ float h_lds[BR][C_SZ + 4];    // 33.3 KB
    __shared__ int   ctok[NW][8][52];        // 13.3 KB compacted tokens
    __shared__ float part[BR][R_SZ][2];
    __shared__ float l_lds[BR][R_SZ];

    const int tid = threadIdx.x;
    const int wave = tid >> 6;
    const int lane = tid & 63;
    const int grp = lane >> 4;   // 16-lane group 0..3
    const int sub = lane & 15;   // float4 slot within a 256 B row
    const int row0 = blockIdx.x * BR;

    // ---------------- token load: 4 rows x 2 sides per wave ----------------
    const int rbase = row0 + wave * 4;
    int lt0 = 0, lt1 = 0, lt2 = 0, lt3 = 0;
    int rt0 = 0, rt1 = 0, rt2 = 0, rt3 = 0;
    int lm0 = 0, lm1 = 0, lm2 = 0, lm3 = 0;
    int rm0 = 0, rm1 = 0, rm2 = 0, rm3 = 0;
    if (lane < L_SZ) {
        const size_t o = (size_t)rbase * L_SZ + lane;
        lt0 = ltok[o];            lm0 = lmask[o];
        lt1 = ltok[o + L_SZ];     lm1 = lmask[o + L_SZ];
        lt2 = ltok[o + 2 * L_SZ]; lm2 = lmask[o + 2 * L_SZ];
        lt3 = ltok[o + 3 * L_SZ]; lm3 = lmask[o + 3 * L_SZ];
        rt0 = rtok[o];            rm0 = rmask[o];
        rt1 = rtok[o + L_SZ];     rm1 = rmask[o + L_SZ];
        rt2 = rtok[o + 2 * L_SZ]; rm2 = rmask[o + 2 * L_SZ];
        rt3 = rtok[o + 3 * L_SZ]; rm3 = rmask[o + 3 * L_SZ];
    }

    // ---------------- compact active tokens into LDS ----------------
    const unsigned long long ltm = (1ULL << lane) - 1;  // lanes below me
    int cnt[8];
#define COMPACT(s, m, t)                                               \
    {                                                                  \
        unsigned long long bal = __ballot((m) != 0);                   \
        cnt[s] = __popcll(bal);                                        \
        if ((m) != 0) ctok[wave][s][__popcll(bal & ltm)] = (t);        \
        if (lane == 0 && cnt[s] == 0) ctok[wave][s][0] = 0;            \
    }
    COMPACT(0, lm0, lt0) COMPACT(1, lm1, lt1)
    COMPACT(2, lm2, lt2) COMPACT(3, lm3, lt3)
    COMPACT(4, rm0, rt0) COMPACT(5, rm1, rt1)
    COMPACT(6, rm2, rt2) COMPACT(7, rm3, rt3)
#undef COMPACT

    int maxc = cnt[0];
#pragma unroll
    for (int s = 1; s < 8; ++s) maxc = max(maxc, cnt[s]);

    // ---------------- gather hot loop: branch-free, 8 loads/iter ----------
    const float4* E = (const float4*)E16;  // [V][16] float4 (8 halves each)
    float aL0[8] = {0}, aL1[8] = {0}, aL2[8] = {0}, aL3[8] = {0};
    float aR0[8] = {0}, aR1[8] = {0}, aR2[8] = {0}, aR3[8] = {0};

    const int nit = (maxc + 3) >> 2;
    for (int it = 0; it < nit; ++it) {
        const int idx = it * 4 + grp;
#define GATH(s, A)                                                      \
        {                                                               \
            int ii = min(idx, cnt[s] - 1); ii = (ii < 0) ? 0 : ii;      \
            const int t_ = ctok[wave][s][ii];                           \
            const float sc = (idx < cnt[s]) ? 1.f : 0.f;                \
            const float4 ev = E[((size_t)t_ << 4) + sub];               \
            const __half2* hp = (const __half2*)&ev;                    \
            _Pragma("unroll")                                           \
            for (int q = 0; q < 4; ++q) {                               \
                A[2 * q]     = fmaf(sc, __half2float(hp[q].x), A[2 * q]);     \
                A[2 * q + 1] = fmaf(sc, __half2float(hp[q].y), A[2 * q + 1]); \
            }                                                           \
        }
        GATH(0, aL0) GATH(1, aL1) GATH(2, aL2) GATH(3, aL3)
        GATH(4, aR0) GATH(5, aR1) GATH(6, aR2) GATH(7, aR3)
#undef GATH
    }

    // reduce across the 4 groups (lanes sharing `sub`)
#define RED(A)                                       \
    _Pragma("unroll")                                \
    for (int j = 0; j < 8; ++j) {                    \
        A[j] += __shfl_xor(A[j], 16);                \
        A[j] += __shfl_xor(A[j], 32);                \
    }
    RED(aL0) RED(aL1) RED(aL2) RED(aL3)
    RED(aR0) RED(aR1) RED(aR2) RED(aR3)
#undef RED

    // write X: row dims [0,128)=left, [128,256)=right; group g owns row g
    {
        const int r = wave * 4;
#define ST(A, row, side)                                                   \
        *(float4*)&X_lds[row][(side) * 128 + sub * 8] =                    \
            make_float4(A[0], A[1], A[2], A[3]);                           \
        *(float4*)&X_lds[row][(side) * 128 + sub * 8 + 4] =                \
            make_float4(A[4], A[5], A[6], A[7]);
        if (grp == 0)      { ST(aL0, r + 0, 0) ST(aR0, r + 0, 1) }
        else if (grp == 1) { ST(aL1, r + 1, 0) ST(aR1, r + 1, 1) }
        else if (grp == 2) { ST(aL2, r + 2, 0) ST(aR2, r + 2, 1) }
        else               { ST(aL3, r + 3, 0) ST(aR3, r + 3, 1) }
#undef ST
    }
    __syncthreads();

    // ---------------- GEMM phase: 64 col-groups x 8 row-groups, R=4 --------
    const int cc = (tid & 63) * 4;        // 4 output cols
    const int rr = (tid >> 6) * 4;        // 4 rows
    float acc[4][4] = {{0.f}};
#pragma unroll 2
    for (int k = 0; k < K_SZ; k += 4) {
        float4 w0 = *(const float4*)&Wt[(k + 0) * C_SZ + cc];
        float4 w1 = *(const float4*)&Wt[(k + 1) * C_SZ + cc];
        float4 w2 = *(const float4*)&Wt[(k + 2) * C_SZ + cc];
        float4 w3 = *(const float4*)&Wt[(k + 3) * C_SZ + cc];
        float ws[4][4] = {{w0.x, w0.y, w0.z, w0.w}, {w1.x, w1.y, w1.z, w1.w},
                          {w2.x, w2.y, w2.z, w2.w}, {w3.x, w3.y, w3.z, w3.w}};
#pragma unroll
        for (int i = 0; i < 4; ++i) {
            float4 xv = *(const float4*)&X_lds[rr + i][k];  // broadcast
            float xs[4] = {xv.x, xv.y, xv.z, xv.w};
#pragma unroll
            for (int kk = 0; kk < 4; ++kk) {
#pragma unroll
                for (int j = 0; j < 4; ++j)
                    acc[i][j] = fmaf(xs[kk], ws[kk][j], acc[i][j]);
            }
        }
    }

    // bias + LeakyReLU -> LDS
#pragma unroll
    for (int i = 0; i < 4; ++i) {
        float4 hv;
        float* hp = (float*)&hv;
#pragma unroll
        for (int j = 0; j < 4; ++j) {
            float h = acc[i][j] + b_cpr[cc + j];
            hp[j] = (h >= 0.f) ? h : 0.01f * h;
        }
        *(float4*)&h_lds[rr + i][cc] = hv;
    }
    __syncthreads();

    // ---------------- head: K-split partial dots (2 chunks of 128) --------
    if (tid < BR * R_SZ * 2) {            // 448 threads: (bl, r, chunk)
        const int chunk = tid & 1;
        const int rh = (tid >> 1) % R_SZ;
        const int bl = tid / (R_SZ * 2);
        const float* wr = W_sm + rh * C_SZ;
        const int c0 = chunk * 128;
        float s = 0.f;
#pragma unroll
        for (int c = 0; c < 128; c += 4) {
            float4 hv = *(const float4*)&h_lds[bl][c0 + c];
            s = fmaf(hv.x, wr[c0 + c + 0], s);
            s = fmaf(hv.y, wr[c0 + c + 1], s);
            s = fmaf(hv.z, wr[c0 + c + 2], s);
            s = fmaf(hv.w, wr[c0 + c + 3], s);
        }
        part[bl][rh][chunk] = s;
    }
    __syncthreads();

    if (tid < BR * R_SZ) {                // 224 threads: combine + bias
        const int bl = tid / R_SZ;
        const int rh = tid % R_SZ;
        l_lds[bl][rh] = part[bl][rh][0] + part[bl][rh][1] + b_sm[rh];
    }
    __syncthreads();

    // ---------------- log-softmax over R=7 ----------------
    if (tid < BR) {
        float m = -INFINITY;
#pragma unroll
        for (int rh = 0; rh < R_SZ; ++rh) m = fmaxf(m, l_lds[tid][rh]);
        float se = 0.f;
#pragma unroll
        for (int rh = 0; rh < R_SZ; ++rh) se += expf(l_lds[tid][rh] - m);
        const float lse = m + logf(se);
        const size_t ob = (size_t)(row0 + tid) * R_SZ;
#pragma unroll
        for (int rh = 0; rh < R_SZ; ++rh) out[ob + rh] = l_lds[tid][rh] - lse;
    }
}

// ---------------------------------------------------------------------------
extern "C" void kernel_launch(void* const* d_in, const int* in_sizes, int n_in,
                              void* d_out, int out_size, void* d_ws, size_t ws_size,
                              hipStream_t stream) {
    const int* ltok = (const int*)d_in[0];
    const int* rtok = (const int*)d_in[1];
    const int* lmask = (const int*)d_in[2];
    const int* rmask = (const int*)d_in[3];
    const float* emb = (const float*)d_in[4];
    const float* W_cpr = (const float*)d_in[5];
    const float* b_cpr = (const float*)d_in[6];
    const float* W_sm = (const float*)d_in[7];
    const float* b_sm = (const float*)d_in[8];
    float* out = (float*)d_out;

    const size_t E16_BYTES = (size_t)V_SZ * D_SZ * sizeof(__half);  // 25.6 MB
    __half* E16 = (__half*)d_ws;
    float* Wt = (float*)((char*)d_ws + E16_BYTES);                  // 256 KB

    const int n4 = V_SZ * D_SZ / 4;
    k_convert<<<(n4 + 255) / 256, 256, 0, stream>>>(emb, E16, n4);
    k_transpose<<<dim3(K_SZ / 32, C_SZ / 32), 256, 0, stream>>>(W_cpr, Wt);
    k_fused_h<<<B_SZ / BR, NT, 0, stream>>>(ltok, rtok, lmask, rmask, E16,
                                            Wt, b_cpr, W_sm, b_sm, out);
}